// Round 19
// baseline (247.797 us; speedup 1.0000x reference)
//
#include <hip/hip_runtime.h>
#include <hip/hip_bf16.h>

#define DIM 128

typedef short s16x8 __attribute__((ext_vector_type(8)));
typedef float f32x4 __attribute__((ext_vector_type(4)));

__device__ __forceinline__ ushort f2b(float f) {
    __hip_bfloat16 h = __float2bfloat16(f);
    return *reinterpret_cast<ushort*>(&h);
}
__device__ __forceinline__ uint pk2(float a, float b) {
    return (uint)f2b(a) | ((uint)f2b(b) << 16);
}
__device__ __forceinline__ float bl(uint u) { return __uint_as_float(u << 16); }
__device__ __forceinline__ float bh(uint u) { return __uint_as_float(u & 0xffff0000u); }

// Swizzled byte address inside a [rows][128 bf16] LDS tile (256B rows).
__device__ __forceinline__ int swz(int row, int kelem) {
    int b = row * 256 + kelem * 2;
    return b ^ ((row & 7) << 4);
}
__device__ __forceinline__ s16x8 read_frag(const char* lds, int row, int k0) {
    return *(const s16x8*)(lds + swz(row, k0));
}

// ---------------------------------------------------------------------------
// prep_hist: [0,80) blocks: weight frag-pack; rest: degree histogram.
// atomicAdd return value = edge's rank within its dst bucket (for the
// atomic-free scatter).
// ---------------------------------------------------------------------------
struct WPtrs { const float* w[10]; };

__global__ __launch_bounds__(256) void prep_hist(
    WPtrs p, ushort* __restrict__ out,
    const int* __restrict__ dst_i, const int* __restrict__ dst_u,
    int* __restrict__ cnt, int* __restrict__ rank, int ni, int E)
{
    const int id = blockIdx.x * 256 + threadIdx.x;
    if (id < 20480) {
        const int m = id >> 11;
        const int c = id & 2047;
        const int lane = c & 63;
        const int kb = (c >> 6) & 3;
        const int ct = (c >> 8) & 1;
        const int w = (c >> 9) & 3;
        const int n = w * 32 + ct * 16 + (lane & 15);
        const int k0 = kb * 32 + 8 * (lane >> 4);
        const float* W = p.w[m];
        float v[8];
#pragma unroll
        for (int j = 0; j < 8; ++j) v[j] = W[(size_t)(k0 + j) * 128 + n];
        uint4 u;
        u.x = pk2(v[0], v[1]); u.y = pk2(v[2], v[3]);
        u.z = pk2(v[4], v[5]); u.w = pk2(v[6], v[7]);
        *(uint4*)&out[((size_t)m * 2048 + c) * 8] = u;
    } else {
        const int gid = id - 20480;
        if (gid < E) rank[gid] = atomicAdd(&cnt[dst_i[gid]], 1);
        else if (gid < 2 * E) rank[gid] = atomicAdd(&cnt[ni + dst_u[gid - E]], 1);
    }
}

// Coalesced fragment load: 8 x 16B per thread from frag-ordered weights.
__device__ __forceinline__ void load_bfrag_pk(const ushort* __restrict__ Wf,
                                              s16x8 B[2][4], int w, int l) {
#pragma unroll
    for (int ct = 0; ct < 2; ++ct)
#pragma unroll
        for (int kb = 0; kb < 4; ++kb)
            B[ct][kb] = *(const s16x8*)&Wf[(size_t)(((w * 2 + ct) * 4 + kb) * 64 + l) * 8];
}

__device__ __forceinline__ void stage_f32(const float* __restrict__ src, int r0, int N, char* lds) {
    const int t = threadIdx.x;
    const int r = t >> 2;
    const int k0 = (t & 3) * 32;
    const int row = r0 + r;
#pragma unroll
    for (int c = 0; c < 4; ++c) {
        uint4 u = make_uint4(0, 0, 0, 0);
        if (row < N) {
            const float4 f0 = *(const float4*)&src[(size_t)row * 128 + k0 + c * 8];
            const float4 f1 = *(const float4*)&src[(size_t)row * 128 + k0 + c * 8 + 4];
            u.x = pk2(f0.x, f0.y); u.y = pk2(f0.z, f0.w);
            u.z = pk2(f1.x, f1.y); u.w = pk2(f1.z, f1.w);
        }
        *(uint4*)(lds + swz(r, k0 + c * 8)) = u;
    }
}

__device__ __forceinline__ void stage_b16(const ushort* __restrict__ src, int r0, int N, char* lds) {
    const int t = threadIdx.x;
    const int r = t >> 2;
    const int k0 = (t & 3) * 32;
    const int row = r0 + r;
#pragma unroll
    for (int c = 0; c < 4; ++c) {
        uint4 u = make_uint4(0, 0, 0, 0);
        if (row < N) u = *(const uint4*)&src[(size_t)row * 128 + k0 + c * 8];
        *(uint4*)(lds + swz(r, k0 + c * 8)) = u;
    }
}

// ---------------------------------------------------------------------------
// scatter: ATOMIC-FREE, standalone (round-15 lesson: fusing scatter with proj
// serializes both roles).
// ---------------------------------------------------------------------------
template<typename IT>
__global__ __launch_bounds__(256) void scatter_kernel(
    const int* __restrict__ ei_ui, const int* __restrict__ ei_iu,
    const int* __restrict__ basep, const int* __restrict__ rank,
    IT* __restrict__ bucket, int ni, int E)
{
    const int e = blockIdx.x * 256 + threadIdx.x;
    if (e < E) {
        bucket[basep[ei_ui[E + e]] + rank[e]] = (IT)ei_ui[e];
    } else if (e < 2 * E) {
        bucket[basep[ni + ei_iu[e]] + rank[e]] = (IT)ei_iu[e - E];
    }
}

// ---------------------------------------------------------------------------
// proj3: one block = one (64-row tile, matrix) pair. m=0:K(+kwa), 1:Q, 2:V.
// (256,4) safe: ONE B-frag set live (round-10/11: combined bodies spill).
// ---------------------------------------------------------------------------
__global__ __launch_bounds__(256, 4) void proj3(
    const float* __restrict__ xu, const ushort* __restrict__ wfrag,
    const float* __restrict__ Waui,
    ushort* __restrict__ Ku, ushort* __restrict__ Qu, ushort* __restrict__ Vu,
    float* __restrict__ kwa_u, int n_user, int ntu,
    const float* __restrict__ xi,
    const float* __restrict__ Waiu,
    ushort* __restrict__ Ki, ushort* __restrict__ Qi, ushort* __restrict__ Vi,
    float* __restrict__ kwa_i, int n_item)
{
    __shared__ char at[16384];
    __shared__ float kwp[4][64][4];
    const int b = blockIdx.x;
    const int m = b % 3;
    const int tile = b / 3;
    const bool user = tile < ntu;
    const float* x = user ? xu : xi;
    const int N = user ? n_user : n_item;
    const int tl = user ? tile : tile - ntu;
    const ushort* WF = wfrag + (size_t)(user ? m : m + 3) * 16384;
    ushort* O = user ? (m == 0 ? Ku : (m == 1 ? Qu : Vu))
                     : (m == 0 ? Ki : (m == 1 ? Qi : Vi));
    const float* Wa = user ? Waui : Waiu;
    float* kwa = user ? kwa_u : kwa_i;

    const int t = threadIdx.x, w = t >> 6, l = t & 63;
    const int lr = l & 15, lg = l >> 4;
    const int r0 = tl << 6;

    stage_f32(x, r0, N, at);
    __syncthreads();

    const int col0 = w * 32 + lr, col1 = col0 + 16;
    s16x8 B[2][4];
    load_bfrag_pk(WF, B, w, l);

    if (m == 0) {
        const float4 waA = *(const float4*)&Wa[col0 * 4];
        const float4 waB = *(const float4*)&Wa[col1 * 4];
#pragma unroll
        for (int rt = 0; rt < 4; ++rt) {
            s16x8 af[4];
#pragma unroll
            for (int kb = 0; kb < 4; ++kb)
                af[kb] = read_frag(at, rt * 16 + lr, kb * 32 + 8 * lg);
            const int rbase = r0 + rt * 16 + 4 * lg;
            f32x4 a0 = {0.f, 0.f, 0.f, 0.f}, a1 = {0.f, 0.f, 0.f, 0.f};
#pragma unroll
            for (int kb = 0; kb < 4; ++kb) {
                a0 = __builtin_amdgcn_mfma_f32_16x16x32_bf16(af[kb], B[0][kb], a0, 0, 0, 0);
                a1 = __builtin_amdgcn_mfma_f32_16x16x32_bf16(af[kb], B[1][kb], a1, 0, 0, 0);
            }
#pragma unroll
            for (int j = 0; j < 4; ++j) {
                if (rbase + j < N) {
                    O[(size_t)(rbase + j) * 128 + col0] = f2b(a0[j]);
                    O[(size_t)(rbase + j) * 128 + col1] = f2b(a1[j]);
                }
            }
#pragma unroll
            for (int j = 0; j < 4; ++j) {
                float p0 = a0[j] * waA.x + a1[j] * waB.x;
                float p1 = a0[j] * waA.y + a1[j] * waB.y;
                float p2 = a0[j] * waA.z + a1[j] * waB.z;
                float p3 = a0[j] * waA.w + a1[j] * waB.w;
#pragma unroll
                for (int off = 8; off; off >>= 1) {
                    p0 += __shfl_xor(p0, off);
                    p1 += __shfl_xor(p1, off);
                    p2 += __shfl_xor(p2, off);
                    p3 += __shfl_xor(p3, off);
                }
                if (lr == 0) {
                    kwp[w][rt * 16 + 4 * lg + j][0] = p0;
                    kwp[w][rt * 16 + 4 * lg + j][1] = p1;
                    kwp[w][rt * 16 + 4 * lg + j][2] = p2;
                    kwp[w][rt * 16 + 4 * lg + j][3] = p3;
                }
            }
        }
        __syncthreads();
        if (t < 64 && r0 + t < N) {
            const float s0 = kwp[0][t][0] + kwp[1][t][0] + kwp[2][t][0] + kwp[3][t][0];
            const float s1 = kwp[0][t][1] + kwp[1][t][1] + kwp[2][t][1] + kwp[3][t][1];
            const float s2 = kwp[0][t][2] + kwp[1][t][2] + kwp[2][t][2] + kwp[3][t][2];
            const float s3 = kwp[0][t][3] + kwp[1][t][3] + kwp[2][t][3] + kwp[3][t][3];
            *(float4*)&kwa[(size_t)(r0 + t) * 4] = make_float4(s0, s1, s2, s3);
        }
    } else {
#pragma unroll
        for (int rt = 0; rt < 4; ++rt) {
            s16x8 af[4];
#pragma unroll
            for (int kb = 0; kb < 4; ++kb)
                af[kb] = read_frag(at, rt * 16 + lr, kb * 32 + 8 * lg);
            const int rbase = r0 + rt * 16 + 4 * lg;
            f32x4 a0 = {0.f, 0.f, 0.f, 0.f}, a1 = {0.f, 0.f, 0.f, 0.f};
#pragma unroll
            for (int kb = 0; kb < 4; ++kb) {
                a0 = __builtin_amdgcn_mfma_f32_16x16x32_bf16(af[kb], B[0][kb], a0, 0, 0, 0);
                a1 = __builtin_amdgcn_mfma_f32_16x16x32_bf16(af[kb], B[1][kb], a1, 0, 0, 0);
            }
#pragma unroll
            for (int j = 0; j < 4; ++j) {
                if (rbase + j < N) {
                    O[(size_t)(rbase + j) * 128 + col0] = f2b(a0[j]);
                    O[(size_t)(rbase + j) * 128 + col1] = f2b(a1[j]);
                }
            }
        }
    }
}

// ---------------------------------------------------------------------------
__global__ __launch_bounds__(256) void alloc_kernel(
    const int* __restrict__ cnt, int* __restrict__ base,
    int* __restrict__ cursor, int n)
{
    const int d = blockIdx.x * blockDim.x + threadIdx.x;
    const int lane = threadIdx.x & 63;
    int c = (d < n) ? cnt[d] : 0;
    int sc = c;
#pragma unroll
    for (int off = 1; off < 64; off <<= 1) {
        int t = __shfl_up(sc, off);
        if (lane >= off) sc += t;
    }
    const int total = __shfl(sc, 63);
    int wb = 0;
    if (lane == 63) wb = atomicAdd(cursor, total);
    wb = __shfl(wb, 63);
    if (d < n) base[d] = wb + sc - c;
}

// ---------------------------------------------------------------------------
// agg8: one 8-lane group per dst; lane li owns 16 dims (head = li>>1).
// 2-WIDE x 2-DEEP pipeline: edges i,i+1 computed while i+2,i+3's loads are
// in flight — doubles per-wave MLP (round-18: occupancy lever exhausted at
// 47%, bound raising is a no-op; per-wave outstanding loads is the lever).
// (256,4): ~110 regs fits the 128 cap (round-17 lesson: 64-reg cap spills).
// ---------------------------------------------------------------------------
__device__ __forceinline__ void unpack8(uint4 u, float* q) {
    q[0] = bl(u.x); q[1] = bh(u.x); q[2] = bl(u.y); q[3] = bh(u.y);
    q[4] = bl(u.z); q[5] = bh(u.z); q[6] = bl(u.w); q[7] = bh(u.w);
}
__device__ __forceinline__ float dot8(uint4 u, const float* q) {
    return bl(u.x) * q[0] + bh(u.x) * q[1] + bl(u.y) * q[2] + bh(u.y) * q[3]
         + bl(u.z) * q[4] + bh(u.z) * q[5] + bl(u.w) * q[6] + bh(u.w) * q[7];
}
__device__ __forceinline__ void acc8(uint4 u, float a, float* acc) {
    acc[0] += a * bl(u.x); acc[1] += a * bh(u.x);
    acc[2] += a * bl(u.y); acc[3] += a * bh(u.y);
    acc[4] += a * bl(u.z); acc[5] += a * bh(u.z);
    acc[6] += a * bl(u.w); acc[7] += a * bh(u.w);
}

template<typename IT>
__global__ __launch_bounds__(256, 4) void agg8_kernel(
    const int* __restrict__ base, const int* __restrict__ cnt, const IT* __restrict__ bsrc,
    const ushort* __restrict__ Ku, const ushort* __restrict__ Qi, const ushort* __restrict__ Vu,
    const float* __restrict__ kwa_u, ushort* __restrict__ msgA,
    const ushort* __restrict__ Ki, const ushort* __restrict__ Qu, const ushort* __restrict__ Vi,
    const float* __restrict__ kwa_i, ushort* __restrict__ msgB,
    int n_item, int ntot)
{
    const int gid = (int)((blockIdx.x * blockDim.x + threadIdx.x) >> 3);
    if (gid >= ntot) return;
    const int li = threadIdx.x & 7;
    const bool item_side = gid < n_item;
    const int d = item_side ? gid : gid - n_item;
    const ushort* K  = item_side ? Ku : Ki;
    const ushort* Q  = item_side ? Qi : Qu;
    const ushort* V  = item_side ? Vu : Vi;
    const float* kwa = item_side ? kwa_u : kwa_i;
    ushort* msg      = item_side ? msgA : msgB;

    const float inv = 0.17677669529663687f;   // 1/sqrt(32)
    const int doff = li * 16;
    const int h = li >> 1;

    float q[16];
    {
        const uint4* qp = (const uint4*)&Q[(size_t)d * 128 + doff];
        unpack8(qp[0], &q[0]);
        unpack8(qp[1], &q[8]);
    }
    float acc[16];
#pragma unroll
    for (int m = 0; m < 16; ++m) acc[m] = 0.f;

    const int b = base[gid], c = cnt[gid];
    if (c > 0) {
        const int s0 = (int)bsrc[b];                        // fallback node
        // preload stages A (edge 0) and B (edge 1; dup edge 0 if absent)
        int sB1 = (1 < c) ? (int)bsrc[b + 1] : s0;
        const uint4* kpA = (const uint4*)&K[(size_t)s0 * 128 + doff];
        const uint4* vpA = (const uint4*)&V[(size_t)s0 * 128 + doff];
        const uint4* kpB = (const uint4*)&K[(size_t)sB1 * 128 + doff];
        const uint4* vpB = (const uint4*)&V[(size_t)sB1 * 128 + doff];
        uint4 kA0 = kpA[0], kA1 = kpA[1], vA0 = vpA[0], vA1 = vpA[1];
        uint4 kB0 = kpB[0], kB1 = kpB[1], vB0 = vpB[0], vB1 = vpB[1];
        float kwA = kwa[(size_t)s0 * 4 + h];
        float kwB = kwa[(size_t)sB1 * 4 + h];

        for (int i = 0; i < c; i += 2) {
            // ---- prefetch edges i+2, i+3 ----
            const int s2 = (i + 2 < c) ? (int)bsrc[b + i + 2] : s0;
            const int s3 = (i + 3 < c) ? (int)bsrc[b + i + 3] : s0;
            const uint4* kp2 = (const uint4*)&K[(size_t)s2 * 128 + doff];
            const uint4* vp2 = (const uint4*)&V[(size_t)s2 * 128 + doff];
            const uint4* kp3 = (const uint4*)&K[(size_t)s3 * 128 + doff];
            const uint4* vp3 = (const uint4*)&V[(size_t)s3 * 128 + doff];
            const uint4 kn20 = kp2[0], kn21 = kp2[1], vn20 = vp2[0], vn21 = vp2[1];
            const uint4 kn30 = kp3[0], kn31 = kp3[1], vn30 = vp3[0], vn31 = vp3[1];
            const float kw2 = kwa[(size_t)s2 * 4 + h];
            const float kw3 = kwa[(size_t)s3 * 4 + h];

            // ---- compute edges i (A) and i+1 (B) ----
            float pA = dot8(kA0, &q[0]) + dot8(kA1, &q[8]);
            float pB = dot8(kB0, &q[0]) + dot8(kB1, &q[8]);
            pA += __shfl_xor(pA, 1);
            pB += __shfl_xor(pB, 1);
            const float eA = __expf(pA * inv + kwA);
            const float eB = __expf(pB * inv + kwB);
            float esA = eA + __shfl_xor(eA, 2);
            float esB = eB + __shfl_xor(eB, 2);
            esA += __shfl_xor(esA, 4);
            esB += __shfl_xor(esB, 4);
            const float attA = __fdividef(eA, esA);
            const float attB = (i + 1 < c) ? __fdividef(eB, esB) : 0.f;
            acc8(vA0, attA, &acc[0]);
            acc8(vA1, attA, &acc[8]);
            acc8(vB0, attB, &acc[0]);
            acc8(vB1, attB, &acc[8]);

            kA0 = kn20; kA1 = kn21; vA0 = vn20; vA1 = vn21; kwA = kw2;
            kB0 = kn30; kB1 = kn31; vB0 = vn30; vB1 = vn31; kwB = kw3;
        }
    }

    uint4* mp = (uint4*)&msg[(size_t)d * 128 + doff];
    uint4 o0, o1;
    o0.x = pk2(acc[0], acc[1]);  o0.y = pk2(acc[2], acc[3]);
    o0.z = pk2(acc[4], acc[5]);  o0.w = pk2(acc[6], acc[7]);
    o1.x = pk2(acc[8], acc[9]);  o1.y = pk2(acc[10], acc[11]);
    o1.z = pk2(acc[12], acc[13]); o1.w = pk2(acc[14], acc[15]);
    mp[0] = o0;
    mp[1] = o1;
}

// ---------------------------------------------------------------------------
// postm: tmp = (msg@Wm)*rs + bm  (bf16 out). Single B-frag body -> (256,4)
// spill-safe. Item tiles [0,nti), user tiles [nti,...).
// ---------------------------------------------------------------------------
__global__ __launch_bounds__(256, 4) void postm_kernel(
    const ushort* __restrict__ msgA, const int* __restrict__ cnt_i,
    const ushort* __restrict__ wfrag, const float* __restrict__ bmi,
    ushort* __restrict__ tmpA, int n_item, int nti,
    const ushort* __restrict__ msgB, const int* __restrict__ cnt_u,
    const float* __restrict__ bmu, ushort* __restrict__ tmpB, int n_user)
{
    __shared__ char at[16384];
    const int b = blockIdx.x;
    const bool item = b < nti;
    const ushort* A = item ? msgA : msgB;
    const int* deg = item ? cnt_i : cnt_u;
    const ushort* WF = wfrag + (size_t)(item ? 6 : 8) * 16384;
    const float* bm = item ? bmi : bmu;
    ushort* T = item ? tmpA : tmpB;
    const int N = item ? n_item : n_user;
    const int tile = item ? b : b - nti;

    const int t = threadIdx.x, w = t >> 6, l = t & 63;
    const int lr = l & 15, lg = l >> 4;
    const int r0 = tile << 6;

    stage_b16(A, r0, N, at);
    __syncthreads();

    const int col0 = w * 32 + lr, col1 = col0 + 16;
    s16x8 B[2][4];
    load_bfrag_pk(WF, B, w, l);
    const float bm0 = bm[col0], bm1 = bm[col1];

#pragma unroll
    for (int rt = 0; rt < 4; ++rt) {
        s16x8 af[4];
#pragma unroll
        for (int kb = 0; kb < 4; ++kb)
            af[kb] = read_frag(at, rt * 16 + lr, kb * 32 + 8 * lg);
        const int rbase = r0 + rt * 16 + 4 * lg;
        float rs[4];
#pragma unroll
        for (int j = 0; j < 4; ++j)
            rs[j] = (rbase + j < N) ? 1.0f / fmaxf((float)deg[rbase + j], 1e-8f) : 0.f;
        f32x4 a0 = {0.f, 0.f, 0.f, 0.f}, a1 = {0.f, 0.f, 0.f, 0.f};
#pragma unroll
        for (int kb = 0; kb < 4; ++kb) {
            a0 = __builtin_amdgcn_mfma_f32_16x16x32_bf16(af[kb], B[0][kb], a0, 0, 0, 0);
            a1 = __builtin_amdgcn_mfma_f32_16x16x32_bf16(af[kb], B[1][kb], a1, 0, 0, 0);
        }
#pragma unroll
        for (int j = 0; j < 4; ++j) {
            if (rbase + j < N) {
                T[(size_t)(rbase + j) * 128 + col0] = f2b(a0[j] * rs[j] + bm0);
                T[(size_t)(rbase + j) * 128 + col1] = f2b(a1[j] * rs[j] + bm1);
            }
        }
    }
}

// ---------------------------------------------------------------------------
// postg: out = LN(tmp@Wg + bg + resid)*gamma + beta. NO launch_bounds (the
// LN state needs ~130 VGPR; bounding spills — round-11 post-mortem).
// ---------------------------------------------------------------------------
__global__ void postg_kernel(
    const ushort* __restrict__ tmpA, const ushort* __restrict__ wfrag,
    const float* __restrict__ bgi, const float* __restrict__ xi,
    const float* __restrict__ lngi, const float* __restrict__ lnbi,
    float* __restrict__ out_item, int n_item, int nti,
    const ushort* __restrict__ tmpB, const float* __restrict__ bgu,
    const float* __restrict__ xu, const float* __restrict__ lngu,
    const float* __restrict__ lnbu, float* __restrict__ out_user, int n_user)
{
    __shared__ char at[16384];
    __shared__ float2 part[4][64];
    __shared__ float2 lnp[64];
    const int b = blockIdx.x;
    const bool item = b < nti;
    const ushort* A = item ? tmpA : tmpB;
    const ushort* WF = wfrag + (size_t)(item ? 7 : 9) * 16384;
    const float* bg = item ? bgi : bgu;
    const float* resid = item ? xi : xu;
    const float* gamma = item ? lngi : lngu;
    const float* beta = item ? lnbi : lnbu;
    float* out = item ? out_item : out_user;
    const int N = item ? n_item : n_user;
    const int tile = item ? b : b - nti;

    const int t = threadIdx.x, w = t >> 6, l = t & 63;
    const int lr = l & 15, lg = l >> 4;
    const int r0 = tile << 6;

    stage_b16(A, r0, N, at);
    __syncthreads();

    const int col0 = w * 32 + lr, col1 = col0 + 16;
    s16x8 B[2][4];
    load_bfrag_pk(WF, B, w, l);
    const float bg0 = bg[col0], bg1 = bg[col1];

    float v[4][2][4];
#pragma unroll
    for (int rt = 0; rt < 4; ++rt) {
        s16x8 af[4];
#pragma unroll
        for (int kb = 0; kb < 4; ++kb)
            af[kb] = read_frag(at, rt * 16 + lr, kb * 32 + 8 * lg);
        const int rbase = r0 + rt * 16 + 4 * lg;
        f32x4 a0 = {0.f, 0.f, 0.f, 0.f}, a1 = {0.f, 0.f, 0.f, 0.f};
#pragma unroll
        for (int kb = 0; kb < 4; ++kb) {
            a0 = __builtin_amdgcn_mfma_f32_16x16x32_bf16(af[kb], B[0][kb], a0, 0, 0, 0);
            a1 = __builtin_amdgcn_mfma_f32_16x16x32_bf16(af[kb], B[1][kb], a1, 0, 0, 0);
        }
#pragma unroll
        for (int j = 0; j < 4; ++j) {
            const bool ok = (rbase + j < N);
            const float rv0 = ok ? resid[(size_t)(rbase + j) * 128 + col0] : 0.f;
            const float rv1 = ok ? resid[(size_t)(rbase + j) * 128 + col1] : 0.f;
            v[rt][0][j] = a0[j] + bg0 + rv0;
            v[rt][1][j] = a1[j] + bg1 + rv1;
        }
    }
#pragma unroll
    for (int rt = 0; rt < 4; ++rt)
#pragma unroll
        for (int j = 0; j < 4; ++j) {
            float s = v[rt][0][j] + v[rt][1][j];
            float q = v[rt][0][j] * v[rt][0][j] + v[rt][1][j] * v[rt][1][j];
            s += __shfl_xor(s, 8); q += __shfl_xor(q, 8);
            s += __shfl_xor(s, 4); q += __shfl_xor(q, 4);
            s += __shfl_xor(s, 2); q += __shfl_xor(q, 2);
            s += __shfl_xor(s, 1); q += __shfl_xor(q, 1);
            if (lr == 0) part[w][rt * 16 + 4 * lg + j] = make_float2(s, q);
        }
    __syncthreads();
    if (t < 64) {
        const float S = part[0][t].x + part[1][t].x + part[2][t].x + part[3][t].x;
        const float Qq = part[0][t].y + part[1][t].y + part[2][t].y + part[3][t].y;
        const float mu = S * (1.f / 128.f);
        const float var = Qq * (1.f / 128.f) - mu * mu;
        lnp[t] = make_float2(mu, rsqrtf(var + 1e-5f));
    }
    __syncthreads();
    const float g0 = gamma[col0], g1 = gamma[col1];
    const float be0 = beta[col0], be1 = beta[col1];
#pragma unroll
    for (int rt = 0; rt < 4; ++rt) {
        const int rbase = r0 + rt * 16 + 4 * lg;
#pragma unroll
        for (int j = 0; j < 4; ++j) {
            const float2 mp = lnp[rt * 16 + 4 * lg + j];
            if (rbase + j < N) {
                out[(size_t)(rbase + j) * 128 + col0] = (v[rt][0][j] - mp.x) * mp.y * g0 + be0;
                out[(size_t)(rbase + j) * 128 + col1] = (v[rt][1][j] - mp.x) * mp.y * g1 + be1;
            }
        }
    }
}

// ---------------------------------------------------------------------------
extern "C" void kernel_launch(void* const* d_in, const int* in_sizes, int n_in,
                              void* d_out, int out_size, void* d_ws, size_t ws_size,
                              hipStream_t stream)
{
    const float* x_user  = (const float*)d_in[0];
    const float* x_item  = (const float*)d_in[1];
    const int*   ei_ui   = (const int*)d_in[2];
    const int*   ei_iu   = (const int*)d_in[3];
    const float* Wk_user = (const float*)d_in[4];
    const float* Wq_user = (const float*)d_in[5];
    const float* Wv_user = (const float*)d_in[6];
    const float* Wk_item = (const float*)d_in[7];
    const float* Wq_item = (const float*)d_in[8];
    const float* Wv_item = (const float*)d_in[9];
    const float* Wa_ui   = (const float*)d_in[10];
    const float* Wa_iu   = (const float*)d_in[11];
    const float* Wm_user = (const float*)d_in[12];
    const float* bm_user = (const float*)d_in[13];
    const float* Wm_item = (const float*)d_in[14];
    const float* bm_item = (const float*)d_in[15];
    const float* Wg_user = (const float*)d_in[16];
    const float* bg_user = (const float*)d_in[17];
    const float* Wg_item = (const float*)d_in[18];
    const float* bg_item = (const float*)d_in[19];
    const float* lng_user = (const float*)d_in[20];
    const float* lnb_user = (const float*)d_in[21];
    const float* lng_item = (const float*)d_in[22];
    const float* lnb_item = (const float*)d_in[23];

    const int n_user = in_sizes[0] / DIM;
    const int n_item = in_sizes[1] / DIM;
    const int E = in_sizes[2] / 2;
    const int nmax = (n_user > n_item) ? n_user : n_item;
    const int ntot = n_user + n_item;
    const size_t nf = (size_t)nmax * DIM;

    ushort* Ku   = (ushort*)d_ws;
    ushort* Qu   = Ku + nf;
    ushort* Vu   = Qu + nf;
    ushort* Ki   = Vu + nf;
    ushort* Qi   = Ki + nf;
    ushort* Vi   = Qi + nf;
    ushort* msgA = Vi + nf;
    ushort* msgB = msgA + nf;
    float* kwa_u = (float*)(msgB + nf);
    float* kwa_i = kwa_u + (size_t)nmax * 4;
    int* cnt     = (int*)(kwa_i + (size_t)nmax * 4);  // [ntot] items then users
    int* cursor  = cnt + ntot;                        // [4]
    int* basep   = cursor + 4;                        // [ntot]
    int* rank    = basep + ntot;                      // [2E]
    ushort* bucket16 = (ushort*)(rank + 2 * (size_t)E); // [2E]
    ushort* wfrag    = bucket16 + 2 * (size_t)E;      // [10*16384]
    ushort* tmpA = Ku;   // item tmp (Ku dead after agg8)
    ushort* tmpB = Ki;   // user tmp

    float* out_user = (float*)d_out;
    float* out_item = out_user + (size_t)n_user * DIM;

    const dim3 blk(256);
    const int ntu = (n_user + 63) / 64, nti = (n_item + 63) / 64;
    const int histB = (2 * E + 255) / 256;

    hipMemsetAsync(cnt, 0, ((size_t)ntot + 4) * sizeof(int), stream);

    WPtrs wp;
    wp.w[0] = Wk_user; wp.w[1] = Wq_user; wp.w[2] = Wv_user;
    wp.w[3] = Wk_item; wp.w[4] = Wq_item; wp.w[5] = Wv_item;
    wp.w[6] = Wm_item; wp.w[7] = Wg_item;
    wp.w[8] = Wm_user; wp.w[9] = Wg_user;
    prep_hist<<<80 + histB, blk, 0, stream>>>(wp, wfrag, ei_ui + E, ei_iu + E, cnt, rank, n_item, E);

    alloc_kernel<<<(ntot + 255) / 256, blk, 0, stream>>>(cnt, basep, cursor, ntot);

    const int aggB = (ntot * 8 + 255) / 256;
    if (nmax <= 65535) {
        scatter_kernel<ushort><<<histB, blk, 0, stream>>>(
            ei_ui, ei_iu, basep, rank, bucket16, n_item, E);
        proj3<<<3 * (ntu + nti), blk, 0, stream>>>(
            x_user, wfrag, Wa_ui, Ku, Qu, Vu, kwa_u, n_user, ntu,
            x_item, Wa_iu, Ki, Qi, Vi, kwa_i, n_item);
        agg8_kernel<ushort><<<aggB, blk, 0, stream>>>(
            basep, cnt, (const ushort*)bucket16,
            Ku, Qi, Vu, kwa_u, msgA,
            Ki, Qu, Vi, kwa_i, msgB,
            n_item, ntot);
    } else {
        int* bucket32 = (int*)bucket16;
        scatter_kernel<int><<<histB, blk, 0, stream>>>(
            ei_ui, ei_iu, basep, rank, bucket32, n_item, E);
        proj3<<<3 * (ntu + nti), blk, 0, stream>>>(
            x_user, wfrag, Wa_ui, Ku, Qu, Vu, kwa_u, n_user, ntu,
            x_item, Wa_iu, Ki, Qi, Vi, kwa_i, n_item);
        agg8_kernel<int><<<aggB, blk, 0, stream>>>(
            basep, cnt, (const int*)bucket32,
            Ku, Qi, Vu, kwa_u, msgA,
            Ki, Qu, Vi, kwa_i, msgB,
            n_item, ntot);
    }

    postm_kernel<<<nti + ntu, blk, 0, stream>>>(
        msgA, cnt, wfrag, bm_item, tmpA, n_item, nti,
        msgB, cnt + n_item, bm_user, tmpB, n_user);

    postg_kernel<<<nti + ntu, blk, 0, stream>>>(
        tmpA, wfrag, bg_item, x_item, lng_item, lnb_item, out_item, n_item, nti,
        tmpB, bg_user, x_user, lng_user, lnb_user, out_user, n_user);
}

// Round 20
// 242.561 us; speedup vs baseline: 1.0216x; 1.0216x over previous
//
#include <hip/hip_runtime.h>
#include <hip/hip_bf16.h>

#define DIM 128

typedef short s16x8 __attribute__((ext_vector_type(8)));
typedef float f32x4 __attribute__((ext_vector_type(4)));

__device__ __forceinline__ ushort f2b(float f) {
    __hip_bfloat16 h = __float2bfloat16(f);
    return *reinterpret_cast<ushort*>(&h);
}
__device__ __forceinline__ uint pk2(float a, float b) {
    return (uint)f2b(a) | ((uint)f2b(b) << 16);
}
__device__ __forceinline__ float bl(uint u) { return __uint_as_float(u << 16); }
__device__ __forceinline__ float bh(uint u) { return __uint_as_float(u & 0xffff0000u); }

// Swizzled byte address inside a [rows][128 bf16] LDS tile (256B rows).
__device__ __forceinline__ int swz(int row, int kelem) {
    int b = row * 256 + kelem * 2;
    return b ^ ((row & 7) << 4);
}
__device__ __forceinline__ s16x8 read_frag(const char* lds, int row, int k0) {
    return *(const s16x8*)(lds + swz(row, k0));
}

// ---------------------------------------------------------------------------
// prep_hist: [0,80) blocks: weight frag-pack; rest: degree histogram.
// atomicAdd return value = edge's rank within its dst bucket (atomic-free
// scatter downstream).
// ---------------------------------------------------------------------------
struct WPtrs { const float* w[10]; };

__global__ __launch_bounds__(256) void prep_hist(
    WPtrs p, ushort* __restrict__ out,
    const int* __restrict__ dst_i, const int* __restrict__ dst_u,
    int* __restrict__ cnt, int* __restrict__ rank, int ni, int E)
{
    const int id = blockIdx.x * 256 + threadIdx.x;
    if (id < 20480) {
        const int m = id >> 11;
        const int c = id & 2047;
        const int lane = c & 63;
        const int kb = (c >> 6) & 3;
        const int ct = (c >> 8) & 1;
        const int w = (c >> 9) & 3;
        const int n = w * 32 + ct * 16 + (lane & 15);
        const int k0 = kb * 32 + 8 * (lane >> 4);
        const float* W = p.w[m];
        float v[8];
#pragma unroll
        for (int j = 0; j < 8; ++j) v[j] = W[(size_t)(k0 + j) * 128 + n];
        uint4 u;
        u.x = pk2(v[0], v[1]); u.y = pk2(v[2], v[3]);
        u.z = pk2(v[4], v[5]); u.w = pk2(v[6], v[7]);
        *(uint4*)&out[((size_t)m * 2048 + c) * 8] = u;
    } else {
        const int gid = id - 20480;
        if (gid < E) rank[gid] = atomicAdd(&cnt[dst_i[gid]], 1);
        else if (gid < 2 * E) rank[gid] = atomicAdd(&cnt[ni + dst_u[gid - E]], 1);
    }
}

// Coalesced fragment load: 8 x 16B per thread from frag-ordered weights.
__device__ __forceinline__ void load_bfrag_pk(const ushort* __restrict__ Wf,
                                              s16x8 B[2][4], int w, int l) {
#pragma unroll
    for (int ct = 0; ct < 2; ++ct)
#pragma unroll
        for (int kb = 0; kb < 4; ++kb)
            B[ct][kb] = *(const s16x8*)&Wf[(size_t)(((w * 2 + ct) * 4 + kb) * 64 + l) * 8];
}

__device__ __forceinline__ void stage_f32(const float* __restrict__ src, int r0, int N, char* lds) {
    const int t = threadIdx.x;
    const int r = t >> 2;
    const int k0 = (t & 3) * 32;
    const int row = r0 + r;
#pragma unroll
    for (int c = 0; c < 4; ++c) {
        uint4 u = make_uint4(0, 0, 0, 0);
        if (row < N) {
            const float4 f0 = *(const float4*)&src[(size_t)row * 128 + k0 + c * 8];
            const float4 f1 = *(const float4*)&src[(size_t)row * 128 + k0 + c * 8 + 4];
            u.x = pk2(f0.x, f0.y); u.y = pk2(f0.z, f0.w);
            u.z = pk2(f1.x, f1.y); u.w = pk2(f1.z, f1.w);
        }
        *(uint4*)(lds + swz(r, k0 + c * 8)) = u;
    }
}

__device__ __forceinline__ void stage_b16(const ushort* __restrict__ src, int r0, int N, char* lds) {
    const int t = threadIdx.x;
    const int r = t >> 2;
    const int k0 = (t & 3) * 32;
    const int row = r0 + r;
#pragma unroll
    for (int c = 0; c < 4; ++c) {
        uint4 u = make_uint4(0, 0, 0, 0);
        if (row < N) u = *(const uint4*)&src[(size_t)row * 128 + k0 + c * 8];
        *(uint4*)(lds + swz(r, k0 + c * 8)) = u;
    }
}

// ---------------------------------------------------------------------------
// scatter: ATOMIC-FREE, standalone.
// ---------------------------------------------------------------------------
template<typename IT>
__global__ __launch_bounds__(256) void scatter_kernel(
    const int* __restrict__ ei_ui, const int* __restrict__ ei_iu,
    const int* __restrict__ basep, const int* __restrict__ rank,
    IT* __restrict__ bucket, int ni, int E)
{
    const int e = blockIdx.x * 256 + threadIdx.x;
    if (e < E) {
        bucket[basep[ei_ui[E + e]] + rank[e]] = (IT)ei_ui[e];
    } else if (e < 2 * E) {
        bucket[basep[ni + ei_iu[e]] + rank[e]] = (IT)ei_iu[e - E];
    }
}

// ---------------------------------------------------------------------------
// proj3: one block = one (64-row tile, matrix) pair. m=0:K(+kwa), 1:Q, 2:V.
// K and V write into an INTERLEAVED KV buffer [n][256]: row = K(128)||V(128)
// so agg's per-edge gather is one contiguous 512B region (round-19: the
// two separate 256B random streams re-fetched ~3x from HBM).
// (256,4) safe: ONE B-frag set live.
// ---------------------------------------------------------------------------
__global__ __launch_bounds__(256, 4) void proj3(
    const float* __restrict__ xu, const ushort* __restrict__ wfrag,
    const float* __restrict__ Waui,
    ushort* __restrict__ KVu, ushort* __restrict__ Qu,
    float* __restrict__ kwa_u, int n_user, int ntu,
    const float* __restrict__ xi,
    const float* __restrict__ Waiu,
    ushort* __restrict__ KVi, ushort* __restrict__ Qi,
    float* __restrict__ kwa_i, int n_item)
{
    __shared__ char at[16384];
    __shared__ float kwp[4][64][4];
    const int b = blockIdx.x;
    const int m = b % 3;
    const int tile = b / 3;
    const bool user = tile < ntu;
    const float* x = user ? xu : xi;
    const int N = user ? n_user : n_item;
    const int tl = user ? tile : tile - ntu;
    const ushort* WF = wfrag + (size_t)(user ? m : m + 3) * 16384;
    ushort* O;
    int ostr, ooff;
    if (m == 1) { O = user ? Qu : Qi; ostr = 128; ooff = 0; }
    else        { O = user ? KVu : KVi; ostr = 256; ooff = (m == 2) ? 128 : 0; }
    const float* Wa = user ? Waui : Waiu;
    float* kwa = user ? kwa_u : kwa_i;

    const int t = threadIdx.x, w = t >> 6, l = t & 63;
    const int lr = l & 15, lg = l >> 4;
    const int r0 = tl << 6;

    stage_f32(x, r0, N, at);
    __syncthreads();

    const int col0 = w * 32 + lr, col1 = col0 + 16;
    s16x8 B[2][4];
    load_bfrag_pk(WF, B, w, l);

    if (m == 0) {
        const float4 waA = *(const float4*)&Wa[col0 * 4];
        const float4 waB = *(const float4*)&Wa[col1 * 4];
#pragma unroll
        for (int rt = 0; rt < 4; ++rt) {
            s16x8 af[4];
#pragma unroll
            for (int kb = 0; kb < 4; ++kb)
                af[kb] = read_frag(at, rt * 16 + lr, kb * 32 + 8 * lg);
            const int rbase = r0 + rt * 16 + 4 * lg;
            f32x4 a0 = {0.f, 0.f, 0.f, 0.f}, a1 = {0.f, 0.f, 0.f, 0.f};
#pragma unroll
            for (int kb = 0; kb < 4; ++kb) {
                a0 = __builtin_amdgcn_mfma_f32_16x16x32_bf16(af[kb], B[0][kb], a0, 0, 0, 0);
                a1 = __builtin_amdgcn_mfma_f32_16x16x32_bf16(af[kb], B[1][kb], a1, 0, 0, 0);
            }
#pragma unroll
            for (int j = 0; j < 4; ++j) {
                if (rbase + j < N) {
                    O[(size_t)(rbase + j) * 256 + col0] = f2b(a0[j]);
                    O[(size_t)(rbase + j) * 256 + col1] = f2b(a1[j]);
                }
            }
#pragma unroll
            for (int j = 0; j < 4; ++j) {
                float p0 = a0[j] * waA.x + a1[j] * waB.x;
                float p1 = a0[j] * waA.y + a1[j] * waB.y;
                float p2 = a0[j] * waA.z + a1[j] * waB.z;
                float p3 = a0[j] * waA.w + a1[j] * waB.w;
#pragma unroll
                for (int off = 8; off; off >>= 1) {
                    p0 += __shfl_xor(p0, off);
                    p1 += __shfl_xor(p1, off);
                    p2 += __shfl_xor(p2, off);
                    p3 += __shfl_xor(p3, off);
                }
                if (lr == 0) {
                    kwp[w][rt * 16 + 4 * lg + j][0] = p0;
                    kwp[w][rt * 16 + 4 * lg + j][1] = p1;
                    kwp[w][rt * 16 + 4 * lg + j][2] = p2;
                    kwp[w][rt * 16 + 4 * lg + j][3] = p3;
                }
            }
        }
        __syncthreads();
        if (t < 64 && r0 + t < N) {
            const float s0 = kwp[0][t][0] + kwp[1][t][0] + kwp[2][t][0] + kwp[3][t][0];
            const float s1 = kwp[0][t][1] + kwp[1][t][1] + kwp[2][t][1] + kwp[3][t][1];
            const float s2 = kwp[0][t][2] + kwp[1][t][2] + kwp[2][t][2] + kwp[3][t][2];
            const float s3 = kwp[0][t][3] + kwp[1][t][3] + kwp[2][t][3] + kwp[3][t][3];
            *(float4*)&kwa[(size_t)(r0 + t) * 4] = make_float4(s0, s1, s2, s3);
        }
    } else {
#pragma unroll
        for (int rt = 0; rt < 4; ++rt) {
            s16x8 af[4];
#pragma unroll
            for (int kb = 0; kb < 4; ++kb)
                af[kb] = read_frag(at, rt * 16 + lr, kb * 32 + 8 * lg);
            const int rbase = r0 + rt * 16 + 4 * lg;
            f32x4 a0 = {0.f, 0.f, 0.f, 0.f}, a1 = {0.f, 0.f, 0.f, 0.f};
#pragma unroll
            for (int kb = 0; kb < 4; ++kb) {
                a0 = __builtin_amdgcn_mfma_f32_16x16x32_bf16(af[kb], B[0][kb], a0, 0, 0, 0);
                a1 = __builtin_amdgcn_mfma_f32_16x16x32_bf16(af[kb], B[1][kb], a1, 0, 0, 0);
            }
#pragma unroll
            for (int j = 0; j < 4; ++j) {
                if (rbase + j < N) {
                    O[(size_t)(rbase + j) * ostr + ooff + col0] = f2b(a0[j]);
                    O[(size_t)(rbase + j) * ostr + ooff + col1] = f2b(a1[j]);
                }
            }
        }
    }
}

// ---------------------------------------------------------------------------
__global__ __launch_bounds__(256) void alloc_kernel(
    const int* __restrict__ cnt, int* __restrict__ base,
    int* __restrict__ cursor, int n)
{
    const int d = blockIdx.x * blockDim.x + threadIdx.x;
    const int lane = threadIdx.x & 63;
    int c = (d < n) ? cnt[d] : 0;
    int sc = c;
#pragma unroll
    for (int off = 1; off < 64; off <<= 1) {
        int t = __shfl_up(sc, off);
        if (lane >= off) sc += t;
    }
    const int total = __shfl(sc, 63);
    int wb = 0;
    if (lane == 63) wb = atomicAdd(cursor, total);
    wb = __shfl(wb, 63);
    if (d < n) base[d] = wb + sc - c;
}

// ---------------------------------------------------------------------------
// agg8: one 8-lane group per dst; lane li owns 16 dims (head = li>>1).
// 1-wide 2-deep pipeline (round-19: 2-wide regressed via reg pressure).
// K/V read from the interleaved KV row: one contiguous 512B gather/edge.
// (256,4): fits without spill.
// ---------------------------------------------------------------------------
__device__ __forceinline__ void unpack8(uint4 u, float* q) {
    q[0] = bl(u.x); q[1] = bh(u.x); q[2] = bl(u.y); q[3] = bh(u.y);
    q[4] = bl(u.z); q[5] = bh(u.z); q[6] = bl(u.w); q[7] = bh(u.w);
}
__device__ __forceinline__ float dot8(uint4 u, const float* q) {
    return bl(u.x) * q[0] + bh(u.x) * q[1] + bl(u.y) * q[2] + bh(u.y) * q[3]
         + bl(u.z) * q[4] + bh(u.z) * q[5] + bl(u.w) * q[6] + bh(u.w) * q[7];
}
__device__ __forceinline__ void acc8(uint4 u, float a, float* acc) {
    acc[0] += a * bl(u.x); acc[1] += a * bh(u.x);
    acc[2] += a * bl(u.y); acc[3] += a * bh(u.y);
    acc[4] += a * bl(u.z); acc[5] += a * bh(u.z);
    acc[6] += a * bl(u.w); acc[7] += a * bh(u.w);
}

template<typename IT>
__global__ __launch_bounds__(256, 4) void agg8_kernel(
    const int* __restrict__ base, const int* __restrict__ cnt, const IT* __restrict__ bsrc,
    const ushort* __restrict__ KVu, const ushort* __restrict__ Qi,
    const float* __restrict__ kwa_u, ushort* __restrict__ msgA,
    const ushort* __restrict__ KVi, const ushort* __restrict__ Qu,
    const float* __restrict__ kwa_i, ushort* __restrict__ msgB,
    int n_item, int ntot)
{
    const int gid = (int)((blockIdx.x * blockDim.x + threadIdx.x) >> 3);
    if (gid >= ntot) return;
    const int li = threadIdx.x & 7;
    const bool item_side = gid < n_item;
    const int d = item_side ? gid : gid - n_item;
    const ushort* KV = item_side ? KVu : KVi;
    const ushort* Q  = item_side ? Qi : Qu;
    const float* kwa = item_side ? kwa_u : kwa_i;
    ushort* msg      = item_side ? msgA : msgB;

    const float inv = 0.17677669529663687f;   // 1/sqrt(32)
    const int doff = li * 16;
    const int h = li >> 1;

    float q[16];
    {
        const uint4* qp = (const uint4*)&Q[(size_t)d * 128 + doff];
        unpack8(qp[0], &q[0]);
        unpack8(qp[1], &q[8]);
    }
    float acc[16];
#pragma unroll
    for (int m = 0; m < 16; ++m) acc[m] = 0.f;

    const int b = base[gid], c = cnt[gid];
    uint4 kc0, kc1, vc0, vc1;
    float kwc;
    int s = 0;
    if (c > 0) {
        s = (int)bsrc[b];
        const uint4* kp = (const uint4*)&KV[(size_t)s * 256 + doff];
        const uint4* vp = (const uint4*)&KV[(size_t)s * 256 + 128 + doff];
        kc0 = kp[0]; kc1 = kp[1];
        vc0 = vp[0]; vc1 = vp[1];
        kwc = kwa[(size_t)s * 4 + h];
    }

    for (int i = 0; i < c; ++i) {
        const int sn = (i + 1 < c) ? (int)bsrc[b + i + 1] : s;
        const uint4* kp = (const uint4*)&KV[(size_t)sn * 256 + doff];
        const uint4* vp = (const uint4*)&KV[(size_t)sn * 256 + 128 + doff];
        const uint4 kn0 = kp[0], kn1 = kp[1];
        const uint4 vn0 = vp[0], vn1 = vp[1];
        const float kwn = kwa[(size_t)sn * 4 + h];

        float p = dot8(kc0, &q[0]) + dot8(kc1, &q[8]);
        p += __shfl_xor(p, 1);
        const float e = __expf(p * inv + kwc);
        float es = e + __shfl_xor(e, 2);
        es += __shfl_xor(es, 4);
        const float att = __fdividef(e, es);
        acc8(vc0, att, &acc[0]);
        acc8(vc1, att, &acc[8]);

        kc0 = kn0; kc1 = kn1; vc0 = vn0; vc1 = vn1; kwc = kwn;
    }

    uint4* mp = (uint4*)&msg[(size_t)d * 128 + doff];
    uint4 o0, o1;
    o0.x = pk2(acc[0], acc[1]);  o0.y = pk2(acc[2], acc[3]);
    o0.z = pk2(acc[4], acc[5]);  o0.w = pk2(acc[6], acc[7]);
    o1.x = pk2(acc[8], acc[9]);  o1.y = pk2(acc[10], acc[11]);
    o1.z = pk2(acc[12], acc[13]); o1.w = pk2(acc[14], acc[15]);
    mp[0] = o0;
    mp[1] = o1;
}

// ---------------------------------------------------------------------------
// postm: tmp = (msg@Wm)*rs + bm  (bf16 out). (256,4) spill-safe.
// ---------------------------------------------------------------------------
__global__ __launch_bounds__(256, 4) void postm_kernel(
    const ushort* __restrict__ msgA, const int* __restrict__ cnt_i,
    const ushort* __restrict__ wfrag, const float* __restrict__ bmi,
    ushort* __restrict__ tmpA, int n_item, int nti,
    const ushort* __restrict__ msgB, const int* __restrict__ cnt_u,
    const float* __restrict__ bmu, ushort* __restrict__ tmpB, int n_user)
{
    __shared__ char at[16384];
    const int b = blockIdx.x;
    const bool item = b < nti;
    const ushort* A = item ? msgA : msgB;
    const int* deg = item ? cnt_i : cnt_u;
    const ushort* WF = wfrag + (size_t)(item ? 6 : 8) * 16384;
    const float* bm = item ? bmi : bmu;
    ushort* T = item ? tmpA : tmpB;
    const int N = item ? n_item : n_user;
    const int tile = item ? b : b - nti;

    const int t = threadIdx.x, w = t >> 6, l = t & 63;
    const int lr = l & 15, lg = l >> 4;
    const int r0 = tile << 6;

    stage_b16(A, r0, N, at);
    __syncthreads();

    const int col0 = w * 32 + lr, col1 = col0 + 16;
    s16x8 B[2][4];
    load_bfrag_pk(WF, B, w, l);
    const float bm0 = bm[col0], bm1 = bm[col1];

#pragma unroll
    for (int rt = 0; rt < 4; ++rt) {
        s16x8 af[4];
#pragma unroll
        for (int kb = 0; kb < 4; ++kb)
            af[kb] = read_frag(at, rt * 16 + lr, kb * 32 + 8 * lg);
        const int rbase = r0 + rt * 16 + 4 * lg;
        float rs[4];
#pragma unroll
        for (int j = 0; j < 4; ++j)
            rs[j] = (rbase + j < N) ? 1.0f / fmaxf((float)deg[rbase + j], 1e-8f) : 0.f;
        f32x4 a0 = {0.f, 0.f, 0.f, 0.f}, a1 = {0.f, 0.f, 0.f, 0.f};
#pragma unroll
        for (int kb = 0; kb < 4; ++kb) {
            a0 = __builtin_amdgcn_mfma_f32_16x16x32_bf16(af[kb], B[0][kb], a0, 0, 0, 0);
            a1 = __builtin_amdgcn_mfma_f32_16x16x32_bf16(af[kb], B[1][kb], a1, 0, 0, 0);
        }
#pragma unroll
        for (int j = 0; j < 4; ++j) {
            if (rbase + j < N) {
                T[(size_t)(rbase + j) * 128 + col0] = f2b(a0[j] * rs[j] + bm0);
                T[(size_t)(rbase + j) * 128 + col1] = f2b(a1[j] * rs[j] + bm1);
            }
        }
    }
}

// ---------------------------------------------------------------------------
// postg: out = LN(tmp@Wg + bg + resid)*gamma + beta. NO launch_bounds
// (round-11: bounding the LN body spills).
// ---------------------------------------------------------------------------
__global__ void postg_kernel(
    const ushort* __restrict__ tmpA, const ushort* __restrict__ wfrag,
    const float* __restrict__ bgi, const float* __restrict__ xi,
    const float* __restrict__ lngi, const float* __restrict__ lnbi,
    float* __restrict__ out_item, int n_item, int nti,
    const ushort* __restrict__ tmpB, const float* __restrict__ bgu,
    const float* __restrict__ xu, const float* __restrict__ lngu,
    const float* __restrict__ lnbu, float* __restrict__ out_user, int n_user)
{
    __shared__ char at[16384];
    __shared__ float2 part[4][64];
    __shared__ float2 lnp[64];
    const int b = blockIdx.x;
    const bool item = b < nti;
    const ushort* A = item ? tmpA : tmpB;
    const ushort* WF = wfrag + (size_t)(item ? 7 : 9) * 16384;
    const float* bg = item ? bgi : bgu;
    const float* resid = item ? xi : xu;
    const float* gamma = item ? lngi : lngu;
    const float* beta = item ? lnbi : lnbu;
    float* out = item ? out_item : out_user;
    const int N = item ? n_item : n_user;
    const int tile = item ? b : b - nti;

    const int t = threadIdx.x, w = t >> 6, l = t & 63;
    const int lr = l & 15, lg = l >> 4;
    const int r0 = tile << 6;

    stage_b16(A, r0, N, at);
    __syncthreads();

    const int col0 = w * 32 + lr, col1 = col0 + 16;
    s16x8 B[2][4];
    load_bfrag_pk(WF, B, w, l);
    const float bg0 = bg[col0], bg1 = bg[col1];

    float v[4][2][4];
#pragma unroll
    for (int rt = 0; rt < 4; ++rt) {
        s16x8 af[4];
#pragma unroll
        for (int kb = 0; kb < 4; ++kb)
            af[kb] = read_frag(at, rt * 16 + lr, kb * 32 + 8 * lg);
        const int rbase = r0 + rt * 16 + 4 * lg;
        f32x4 a0 = {0.f, 0.f, 0.f, 0.f}, a1 = {0.f, 0.f, 0.f, 0.f};
#pragma unroll
        for (int kb = 0; kb < 4; ++kb) {
            a0 = __builtin_amdgcn_mfma_f32_16x16x32_bf16(af[kb], B[0][kb], a0, 0, 0, 0);
            a1 = __builtin_amdgcn_mfma_f32_16x16x32_bf16(af[kb], B[1][kb], a1, 0, 0, 0);
        }
#pragma unroll
        for (int j = 0; j < 4; ++j) {
            const bool ok = (rbase + j < N);
            const float rv0 = ok ? resid[(size_t)(rbase + j) * 128 + col0] : 0.f;
            const float rv1 = ok ? resid[(size_t)(rbase + j) * 128 + col1] : 0.f;
            v[rt][0][j] = a0[j] + bg0 + rv0;
            v[rt][1][j] = a1[j] + bg1 + rv1;
        }
    }
#pragma unroll
    for (int rt = 0; rt < 4; ++rt)
#pragma unroll
        for (int j = 0; j < 4; ++j) {
            float s = v[rt][0][j] + v[rt][1][j];
            float q = v[rt][0][j] * v[rt][0][j] + v[rt][1][j] * v[rt][1][j];
            s += __shfl_xor(s, 8); q += __shfl_xor(q, 8);
            s += __shfl_xor(s, 4); q += __shfl_xor(q, 4);
            s += __shfl_xor(s, 2); q += __shfl_xor(q, 2);
            s += __shfl_xor(s, 1); q += __shfl_xor(q, 1);
            if (lr == 0) part[w][rt * 16 + 4 * lg + j] = make_float2(s, q);
        }
    __syncthreads();
    if (t < 64) {
        const float S = part[0][t].x + part[1][t].x + part[2][t].x + part[3][t].x;
        const float Qq = part[0][t].y + part[1][t].y + part[2][t].y + part[3][t].y;
        const float mu = S * (1.f / 128.f);
        const float var = Qq * (1.f / 128.f) - mu * mu;
        lnp[t] = make_float2(mu, rsqrtf(var + 1e-5f));
    }
    __syncthreads();
    const float g0 = gamma[col0], g1 = gamma[col1];
    const float be0 = beta[col0], be1 = beta[col1];
#pragma unroll
    for (int rt = 0; rt < 4; ++rt) {
        const int rbase = r0 + rt * 16 + 4 * lg;
#pragma unroll
        for (int j = 0; j < 4; ++j) {
            const float2 mp = lnp[rt * 16 + 4 * lg + j];
            if (rbase + j < N) {
                out[(size_t)(rbase + j) * 128 + col0] = (v[rt][0][j] - mp.x) * mp.y * g0 + be0;
                out[(size_t)(rbase + j) * 128 + col1] = (v[rt][1][j] - mp.x) * mp.y * g1 + be1;
            }
        }
    }
}

// ---------------------------------------------------------------------------
extern "C" void kernel_launch(void* const* d_in, const int* in_sizes, int n_in,
                              void* d_out, int out_size, void* d_ws, size_t ws_size,
                              hipStream_t stream)
{
    const float* x_user  = (const float*)d_in[0];
    const float* x_item  = (const float*)d_in[1];
    const int*   ei_ui   = (const int*)d_in[2];
    const int*   ei_iu   = (const int*)d_in[3];
    const float* Wk_user = (const float*)d_in[4];
    const float* Wq_user = (const float*)d_in[5];
    const float* Wv_user = (const float*)d_in[6];
    const float* Wk_item = (const float*)d_in[7];
    const float* Wq_item = (const float*)d_in[8];
    const float* Wv_item = (const float*)d_in[9];
    const float* Wa_ui   = (const float*)d_in[10];
    const float* Wa_iu   = (const float*)d_in[11];
    const float* Wm_user = (const float*)d_in[12];
    const float* bm_user = (const float*)d_in[13];
    const float* Wm_item = (const float*)d_in[14];
    const float* bm_item = (const float*)d_in[15];
    const float* Wg_user = (const float*)d_in[16];
    const float* bg_user = (const float*)d_in[17];
    const float* Wg_item = (const float*)d_in[18];
    const float* bg_item = (const float*)d_in[19];
    const float* lng_user = (const float*)d_in[20];
    const float* lnb_user = (const float*)d_in[21];
    const float* lng_item = (const float*)d_in[22];
    const float* lnb_item = (const float*)d_in[23];

    const int n_user = in_sizes[0] / DIM;
    const int n_item = in_sizes[1] / DIM;
    const int E = in_sizes[2] / 2;
    const int nmax = (n_user > n_item) ? n_user : n_item;
    const int ntot = n_user + n_item;
    const size_t nf = (size_t)nmax * DIM;

    ushort* KVu  = (ushort*)d_ws;        // [nmax][256]: K||V interleaved
    ushort* KVi  = KVu + 2 * nf;
    ushort* Qu   = KVi + 2 * nf;
    ushort* Qi   = Qu + nf;
    ushort* msgA = Qi + nf;
    ushort* msgB = msgA + nf;
    float* kwa_u = (float*)(msgB + nf);
    float* kwa_i = kwa_u + (size_t)nmax * 4;
    int* cnt     = (int*)(kwa_i + (size_t)nmax * 4);  // [ntot] items then users
    int* cursor  = cnt + ntot;                        // [4]
    int* basep   = cursor + 4;                        // [ntot]
    int* rank    = basep + ntot;                      // [2E]
    ushort* bucket16 = (ushort*)(rank + 2 * (size_t)E); // [2E]
    ushort* wfrag    = bucket16 + 2 * (size_t)E;      // [10*16384]
    ushort* tmpA = KVu;   // item tmp (KVu dead after agg8)
    ushort* tmpB = KVi;   // user tmp

    float* out_user = (float*)d_out;
    float* out_item = out_user + (size_t)n_user * DIM;

    const dim3 blk(256);
    const int ntu = (n_user + 63) / 64, nti = (n_item + 63) / 64;
    const int histB = (2 * E + 255) / 256;

    hipMemsetAsync(cnt, 0, ((size_t)ntot + 4) * sizeof(int), stream);

    WPtrs wp;
    wp.w[0] = Wk_user; wp.w[1] = Wq_user; wp.w[2] = Wv_user;
    wp.w[3] = Wk_item; wp.w[4] = Wq_item; wp.w[5] = Wv_item;
    wp.w[6] = Wm_item; wp.w[7] = Wg_item;
    wp.w[8] = Wm_user; wp.w[9] = Wg_user;
    prep_hist<<<80 + histB, blk, 0, stream>>>(wp, wfrag, ei_ui + E, ei_iu + E, cnt, rank, n_item, E);

    alloc_kernel<<<(ntot + 255) / 256, blk, 0, stream>>>(cnt, basep, cursor, ntot);

    const int aggB = (ntot * 8 + 255) / 256;
    if (nmax <= 65535) {
        scatter_kernel<ushort><<<histB, blk, 0, stream>>>(
            ei_ui, ei_iu, basep, rank, bucket16, n_item, E);
        proj3<<<3 * (ntu + nti), blk, 0, stream>>>(
            x_user, wfrag, Wa_ui, KVu, Qu, kwa_u, n_user, ntu,
            x_item, Wa_iu, KVi, Qi, kwa_i, n_item);
        agg8_kernel<ushort><<<aggB, blk, 0, stream>>>(
            basep, cnt, (const ushort*)bucket16,
            KVu, Qi, kwa_u, msgA,
            KVi, Qu, kwa_i, msgB,
            n_item, ntot);
    } else {
        int* bucket32 = (int*)bucket16;
        scatter_kernel<int><<<histB, blk, 0, stream>>>(
            ei_ui, ei_iu, basep, rank, bucket32, n_item, E);
        proj3<<<3 * (ntu + nti), blk, 0, stream>>>(
            x_user, wfrag, Wa_ui, KVu, Qu, kwa_u, n_user, ntu,
            x_item, Wa_iu, KVi, Qi, kwa_i, n_item);
        agg8_kernel<int><<<aggB, blk, 0, stream>>>(
            basep, cnt, (const int*)bucket32,
            KVu, Qi, kwa_u, msgA,
            KVi, Qu, kwa_i, msgB,
            n_item, ntot);
    }

    postm_kernel<<<nti + ntu, blk, 0, stream>>>(
        msgA, cnt, wfrag, bm_item, tmpA, n_item, nti,
        msgB, cnt + n_item, bm_user, tmpB, n_user);

    postg_kernel<<<nti + ntu, blk, 0, stream>>>(
        tmpA, wfrag, bg_item, x_item, lng_item, lnb_item, out_item, n_item, nti,
        tmpB, bg_user, x_user, lng_user, lnb_user, out_user, n_user);
}